// Round 1
// baseline (4717.771 us; speedup 1.0000x reference)
//
#include <hip/hip_runtime.h>

// Problem constants (fixed by the reference)
#define NU 100000
#define NV 50000
#define KSUP 5
#define ESUP 400000
#define NE 500000
#define DIN 512
#define DGCN 500
#define FSUP 100     // DGCN / KSUP
#define DSIDE 128
#define HSIDE 64
#define DENC 128
#define NBAS 3
#define NCLS 5

#define BM 64
#define BN 64
#define BK 16

// Generic tiled fp32 GEMM, templated on mode:
//  MODE 0: encoder GEMM   C[M,100] = A[M,512] @ Wenc[kSup][512][100]
//  MODE 1: side dense     C[M,64]  = relu(A[M,128] @ B[128,64] + bias)
//  MODE 2: dense2         C[M,128] = concat(relu(hid), side)[M,564] @ B[564,128]
//          A = hid base, layout [5][M][100] (sstride = M*100), A2 = side [M][64]
//  MODE 3: decoder pre    C[M, b*128 + 0..127] = A[M,128] @ dec_W[b], ldc=384
template<int MODE>
__global__ __launch_bounds__(256) void gemm_k(
    const float* __restrict__ A, const float* __restrict__ A2,
    const float* __restrict__ B, const float* __restrict__ bias,
    float* __restrict__ C,
    int M, int N, int K, int lda, int ldb, int ldc, int kSup, int sstride)
{
    __shared__ float As[BK][BM + 4];
    __shared__ float Bs[BK][BN + 4];
    const int t = threadIdx.x;
    const int rowBase = blockIdx.x * BM;
    const int colBase = blockIdx.y * BN;
    const int ty = t >> 4, tx = t & 15;

    const float* Bp = B;
    int colOff = 0;
    if constexpr (MODE == 3) {
        const int b = blockIdx.z;
        Bp = B + (size_t)b * DENC * DENC;
        colOff = b * DENC;
    }

    float acc[4][4] = {};

    for (int k0 = 0; k0 < K; k0 += BK) {
        // ---- load A tile: 64 rows x 16 k (16 threads per row, coalesced in k)
        #pragma unroll
        for (int p = 0; p < 4; ++p) {
            int r  = p * 16 + (t >> 4);
            int kk = t & 15;
            int gr = rowBase + r, gk = k0 + kk;
            float v = 0.f;
            if (gr < M && gk < K) {
                if constexpr (MODE == 2) {
                    if (gk < DGCN) {
                        int s = gk / FSUP, f = gk - s * FSUP;
                        v = fmaxf(A[(size_t)s * sstride + (size_t)gr * FSUP + f], 0.f);
                    } else {
                        v = A2[(size_t)gr * HSIDE + (gk - DGCN)];
                    }
                } else {
                    v = A[(size_t)gr * lda + gk];
                }
            }
            As[kk][r] = v;
        }
        // ---- load B tile: 16 k x 64 cols (64 threads per k-row, coalesced in j)
        #pragma unroll
        for (int p = 0; p < 4; ++p) {
            int kk = p * 4 + (t >> 6);
            int j  = t & 63;
            int gk = k0 + kk, gj = colBase + j;
            float v = 0.f;
            if (gj < N && gk < K) {
                if constexpr (MODE == 0) {
                    v = B[(size_t)kSup * (DIN * FSUP) + (size_t)gk * FSUP + gj];
                } else {
                    v = Bp[(size_t)gk * ldb + gj];
                }
            }
            Bs[kk][j] = v;
        }
        __syncthreads();

        #pragma unroll
        for (int kk = 0; kk < BK; ++kk) {
            float4 a4 = *reinterpret_cast<const float4*>(&As[kk][ty * 4]);
            float4 b4 = *reinterpret_cast<const float4*>(&Bs[kk][tx * 4]);
            float aa[4] = {a4.x, a4.y, a4.z, a4.w};
            float bb[4] = {b4.x, b4.y, b4.z, b4.w};
            #pragma unroll
            for (int i = 0; i < 4; ++i)
                #pragma unroll
                for (int j = 0; j < 4; ++j)
                    acc[i][j] = fmaf(aa[i], bb[j], acc[i][j]);
        }
        __syncthreads();
    }

    #pragma unroll
    for (int i = 0; i < 4; ++i) {
        int gr = rowBase + ty * 4 + i;
        if (gr >= M) continue;
        #pragma unroll
        for (int j = 0; j < 4; ++j) {
            int gc = colBase + tx * 4 + j;
            if (gc >= N) continue;
            float v = acc[i][j];
            if constexpr (MODE == 1) v = fmaxf(v + bias[gc], 0.f);
            C[(size_t)gr * ldc + gc + colOff] = v;
        }
    }
}

// Sparse aggregation for one support (both directions in one pass).
// 32 lanes per edge; tmpU/tmpV are this support's [N][100] slices, hidU/hidV
// are this support's [N][100] output slices.
__global__ __launch_bounds__(256) void agg_k(
    const int* __restrict__ rows, const int* __restrict__ cols,
    const float* __restrict__ vals,
    const float* __restrict__ tmpU, const float* __restrict__ tmpV,
    float* __restrict__ hidU, float* __restrict__ hidV, int nE)
{
    int e = blockIdx.x * 8 + (threadIdx.x >> 5);
    if (e >= nE) return;
    int lane = threadIdx.x & 31;
    int r = rows[e], c = cols[e];
    float v = vals[e];
    const float* tv = tmpV + (size_t)c * FSUP;
    const float* tu = tmpU + (size_t)r * FSUP;
    float* hu = hidU + (size_t)r * FSUP;
    float* hv = hidV + (size_t)c * FSUP;
    #pragma unroll
    for (int i = 0; i < 4; ++i) {
        int f = lane + i * 32;
        if (f < FSUP) {
            atomicAdd(&hu[f], v * tv[f]);
            atomicAdd(&hv[f], v * tu[f]);
        }
    }
}

// Final decoder: basis[b] = dot(Ub[u][b][:], embV[v][:]); out = basis @ cls.
// Ub layout: [NU][3][128] (stride 384). 32 lanes per edge.
__global__ __launch_bounds__(256) void dec_k(
    const int* __restrict__ ue, const int* __restrict__ ie,
    const float* __restrict__ Ub, const float* __restrict__ embV,
    const float* __restrict__ cls, float* __restrict__ out, int nE)
{
    int e = blockIdx.x * 8 + (threadIdx.x >> 5);
    if (e >= nE) return;
    int lane = threadIdx.x & 31;
    int u = ue[e], v = ie[e];
    const float* pv = embV + (size_t)v * DENC;
    float vb[4];
    #pragma unroll
    for (int i = 0; i < 4; ++i) vb[i] = pv[lane + i * 32];
    float basis[NBAS];
    #pragma unroll
    for (int b = 0; b < NBAS; ++b) {
        const float* pu = Ub + (size_t)u * (NBAS * DENC) + b * DENC;
        float s = 0.f;
        #pragma unroll
        for (int i = 0; i < 4; ++i) s += pu[lane + i * 32] * vb[i];
        #pragma unroll
        for (int off = 16; off; off >>= 1) s += __shfl_xor(s, off, 32);
        basis[b] = s;
    }
    if (lane < NCLS) {
        float o = 0.f;
        #pragma unroll
        for (int b = 0; b < NBAS; ++b) o += basis[b] * cls[b * NCLS + lane];
        out[(size_t)e * NCLS + lane] = o;
    }
}

extern "C" void kernel_launch(void* const* d_in, const int* in_sizes, int n_in,
                              void* d_out, int out_size, void* d_ws, size_t ws_size,
                              hipStream_t stream) {
    const int*   sup_u  = (const int*)  d_in[0];   // [5][400000]
    const int*   sup_i  = (const int*)  d_in[1];
    const float* sup_v  = (const float*)d_in[2];
    const float* u_in   = (const float*)d_in[3];   // [NU][512]
    const float* v_in   = (const float*)d_in[4];   // [NV][512]
    const float* u_side = (const float*)d_in[5];   // [NU][128]
    const float* v_side = (const float*)d_in[6];
    const int*   ue     = (const int*)  d_in[7];   // [NE]
    const int*   ie     = (const int*)  d_in[8];
    const float* W_enc  = (const float*)d_in[9];   // [5][512][100]
    const float* Wu1    = (const float*)d_in[10];  // [128][64]
    const float* bu1    = (const float*)d_in[11];
    const float* Wi1    = (const float*)d_in[12];
    const float* bi1    = (const float*)d_in[13];
    const float* Wu2    = (const float*)d_in[14];  // [564][128]
    const float* Wi2    = (const float*)d_in[15];
    const float* dec_W  = (const float*)d_in[16];  // [3][128][128]
    const float* deccls = (const float*)d_in[17];  // [3][5]

    char* ws = (char*)d_ws;
    // layout (bytes):
    //   hidU  @ 0          : 5*NU*100*4 = 200,000,000   [5][NU][100]
    //   hidV  @ 200,000,000: 5*NV*100*4 = 100,000,000   [5][NV][100]
    //   tmpU  @ 300,000,000: NU*100*4   =  40,000,000   per-support slice
    //   tmpV  @ 340,000,000: NV*100*4   =  20,000,000
    //   sideU @ 360,000,000: NU*64*4    =  25,600,000
    //   sideV @ 385,600,000: NV*64*4    =  12,800,000
    //   embU  @ 398,400,000: NU*128*4   =  51,200,000
    //   embV  @ 449,600,000: NV*128*4   =  25,600,000
    //   Ub    @ 0 (reuses dead hidU)    : NU*384*4 = 153,600,000
    float* hidU  = (float*)(ws);
    float* hidV  = (float*)(ws + 200000000LL);
    float* tmpU  = (float*)(ws + 300000000LL);
    float* tmpV  = (float*)(ws + 340000000LL);
    float* sideU = (float*)(ws + 360000000LL);
    float* sideV = (float*)(ws + 385600000LL);
    float* embU  = (float*)(ws + 398400000LL);
    float* embV  = (float*)(ws + 449600000LL);
    float* Ub    = (float*)(ws);

    dim3 blk(256);
    const int gu = (NU + BM - 1) / BM;   // 1563
    const int gv = (NV + BM - 1) / BM;   // 782

    // zero the accumulation buffers (hidU + hidV contiguous)
    hipMemsetAsync(ws, 0, 300000000LL, stream);

    // ---- encoder: per support, GEMM slices then sparse aggregation ----
    for (int k = 0; k < KSUP; ++k) {
        gemm_k<0><<<dim3(gu, 2, 1), blk, 0, stream>>>(
            u_in, nullptr, W_enc, nullptr, tmpU,
            NU, FSUP, DIN, DIN, 0, FSUP, k, 0);
        gemm_k<0><<<dim3(gv, 2, 1), blk, 0, stream>>>(
            v_in, nullptr, W_enc, nullptr, tmpV,
            NV, FSUP, DIN, DIN, 0, FSUP, k, 0);
        agg_k<<<dim3(ESUP / 8), blk, 0, stream>>>(
            sup_u + (size_t)k * ESUP, sup_i + (size_t)k * ESUP, sup_v + (size_t)k * ESUP,
            tmpU, tmpV,
            hidU + (size_t)k * NU * FSUP, hidV + (size_t)k * NV * FSUP, ESUP);
    }

    // ---- side dense (relu + bias) ----
    gemm_k<1><<<dim3(gu, 1, 1), blk, 0, stream>>>(
        u_side, nullptr, Wu1, bu1, sideU, NU, HSIDE, DSIDE, DSIDE, HSIDE, HSIDE, 0, 0);
    gemm_k<1><<<dim3(gv, 1, 1), blk, 0, stream>>>(
        v_side, nullptr, Wi1, bi1, sideV, NV, HSIDE, DSIDE, DSIDE, HSIDE, HSIDE, 0, 0);

    // ---- dense2: concat(relu(hid), side) @ W2 ----
    gemm_k<2><<<dim3(gu, 2, 1), blk, 0, stream>>>(
        hidU, sideU, Wu2, nullptr, embU, NU, DENC, DGCN + HSIDE, 0, DENC, DENC, 0, NU * FSUP);
    gemm_k<2><<<dim3(gv, 2, 1), blk, 0, stream>>>(
        hidV, sideV, Wi2, nullptr, embV, NV, DENC, DGCN + HSIDE, 0, DENC, DENC, 0, NV * FSUP);

    // ---- decoder precompute: Ub[n][b][:] = embU[n] @ dec_W[b]  (overwrites hidU) ----
    gemm_k<3><<<dim3(gu, 2, NBAS), blk, 0, stream>>>(
        embU, nullptr, dec_W, nullptr, Ub, NU, DENC, DENC, DENC, DENC, NBAS * DENC, 0, 0);

    // ---- final decoder over edges ----
    dec_k<<<dim3(NE / 8), blk, 0, stream>>>(
        ue, ie, Ub, embV, deccls, (float*)d_out, NE);
}

// Round 2
// 2967.602 us; speedup vs baseline: 1.5898x; 1.5898x over previous
//
#include <hip/hip_runtime.h>

// Problem constants (fixed by the reference)
#define NU 100000
#define NV 50000
#define KSUP 5
#define ESUP 400000
#define NE 500000
#define DIN 512
#define DGCN 500
#define FSUP 100     // DGCN / KSUP
#define DSIDE 128
#define HSIDE 64
#define DENC 128
#define NBAS 3
#define NCLS 5

__device__ __forceinline__ ushort f2bf(float x) {
    union { float f; unsigned u; } c; c.f = x;
    unsigned r = (c.u + 0x7FFFu + ((c.u >> 16) & 1u)) >> 16;   // RNE
    return (ushort)r;
}
__device__ __forceinline__ float bf2f(ushort h) {
    union { unsigned u; float f; } c; c.u = ((unsigned)h) << 16;
    return c.f;
}

typedef __attribute__((ext_vector_type(4))) float f32x4;
typedef __attribute__((ext_vector_type(8))) short bf16x8;
typedef __attribute__((address_space(3))) void lds_void;
typedef const __attribute__((address_space(1))) void glob_void;

// ---------------------------------------------------------------------------
// bf16 MFMA GEMM: C[M,N] = A[M,K](bf16,K-major) @ BT[N,K](bf16,K-major)^T
// Requirements: K % 64 == 0, N % 128 == 0. M guarded.
// 128x128 tile, BK=64, 4 waves (2x2), per-wave 64x64 via 4x4 frags of 16x16x32.
// LDS tiles XOR-swizzled (byte ^= (row&7)<<4) via pre-swizzled global source
// (global_load_lds writes linearly: rule #21 both-sides involution).
// STORE_BF16: 1 -> C is ushort (bf16), 0 -> C is float.
template<int STORE_BF16>
__global__ __launch_bounds__(256) void gemm_bf16_k(
    const ushort* __restrict__ A, const ushort* __restrict__ BT,
    void* __restrict__ Cout, int M, int N, int K, int ldc)
{
    __shared__ ushort As[128 * 64];
    __shared__ ushort Bs[128 * 64];
    const int t = threadIdx.x;
    const int lane = t & 63;
    const int w = t >> 6;
    const int wr = w >> 1, wc = w & 1;
    const int rowBase = blockIdx.x * 128;
    const int colBase = blockIdx.y * 128;

    f32x4 acc[4][4] = {};

    for (int k0 = 0; k0 < K; k0 += 64) {
        #pragma unroll
        for (int i = 0; i < 4; ++i) {
            int chi = i * 256 + t;                       // 16B chunk index 0..1023
            int r = chi >> 3;                            // tile row
            int c = (((chi >> 3) & 7) ^ (chi & 7)) * 8;  // pre-swizzled k-col (bf16 elems)
            int ga = rowBase + r; if (ga > M - 1) ga = M - 1;
            __builtin_amdgcn_global_load_lds(
                (glob_void*)(A + (size_t)ga * K + k0 + c),
                (lds_void*)(As + (size_t)chi * 8), 16, 0, 0);
            int gb = colBase + r; if (gb > N - 1) gb = N - 1;
            __builtin_amdgcn_global_load_lds(
                (glob_void*)(BT + (size_t)gb * K + k0 + c),
                (lds_void*)(Bs + (size_t)chi * 8), 16, 0, 0);
        }
        __syncthreads();

        #pragma unroll
        for (int kk = 0; kk < 2; ++kk) {
            bf16x8 af[4], bfr[4];
            const int cb2 = (kk * 32 + (lane >> 4) * 8) * 2;   // byte offset of k-chunk
            #pragma unroll
            for (int mi = 0; mi < 4; ++mi) {
                int r = wr * 64 + mi * 16 + (lane & 15);
                int off = (r * 128 + cb2) ^ ((r & 7) << 4);
                af[mi] = *(const bf16x8*)((const char*)As + off);
            }
            #pragma unroll
            for (int nj = 0; nj < 4; ++nj) {
                int r = wc * 64 + nj * 16 + (lane & 15);
                int off = (r * 128 + cb2) ^ ((r & 7) << 4);
                bfr[nj] = *(const bf16x8*)((const char*)Bs + off);
            }
            #pragma unroll
            for (int mi = 0; mi < 4; ++mi)
                #pragma unroll
                for (int nj = 0; nj < 4; ++nj)
                    acc[mi][nj] = __builtin_amdgcn_mfma_f32_16x16x32_bf16(
                        af[mi], bfr[nj], acc[mi][nj], 0, 0, 0);
        }
        __syncthreads();
    }

    // epilogue: C/D layout col=lane&15, row=(lane>>4)*4+q  [m89-verified]
    #pragma unroll
    for (int mi = 0; mi < 4; ++mi) {
        #pragma unroll
        for (int q = 0; q < 4; ++q) {
            int gr = rowBase + wr * 64 + mi * 16 + (lane >> 4) * 4 + q;
            if (gr >= M) continue;
            #pragma unroll
            for (int nj = 0; nj < 4; ++nj) {
                int gc = colBase + wc * 64 + nj * 16 + (lane & 15);
                float v = acc[mi][nj][q];
                if (STORE_BF16)
                    ((ushort*)Cout)[(size_t)gr * ldc + gc] = f2bf(v);
                else
                    ((float*)Cout)[(size_t)gr * ldc + gc] = v;
            }
        }
    }
}

// ---------------------------------------------------------------------------
// fp32 tiled GEMM (kept for side dense only): C = relu(A@B + bias)
#define BM 64
#define BN 64
#define BK 16
__global__ __launch_bounds__(256) void gemm_side_k(
    const float* __restrict__ A, const float* __restrict__ B,
    const float* __restrict__ bias, float* __restrict__ C,
    int M, int N, int K)
{
    __shared__ float As[BK][BM + 4];
    __shared__ float Bs[BK][BN + 4];
    const int t = threadIdx.x;
    const int rowBase = blockIdx.x * BM;
    const int ty = t >> 4, tx = t & 15;
    float acc[4][4] = {};

    for (int k0 = 0; k0 < K; k0 += BK) {
        #pragma unroll
        for (int p = 0; p < 4; ++p) {
            int r = p * 16 + (t >> 4), kk = t & 15;
            int gr = rowBase + r, gk = k0 + kk;
            As[kk][r] = (gr < M && gk < K) ? A[(size_t)gr * K + gk] : 0.f;
        }
        #pragma unroll
        for (int p = 0; p < 4; ++p) {
            int kk = p * 4 + (t >> 6), j = t & 63;
            int gk = k0 + kk;
            Bs[kk][j] = (j < N && gk < K) ? B[(size_t)gk * N + j] : 0.f;
        }
        __syncthreads();
        #pragma unroll
        for (int kk = 0; kk < BK; ++kk) {
            float4 a4 = *reinterpret_cast<const float4*>(&As[kk][ty * 4]);
            float4 b4 = *reinterpret_cast<const float4*>(&Bs[kk][tx * 4]);
            float aa[4] = {a4.x, a4.y, a4.z, a4.w};
            float bb[4] = {b4.x, b4.y, b4.z, b4.w};
            #pragma unroll
            for (int i = 0; i < 4; ++i)
                #pragma unroll
                for (int j = 0; j < 4; ++j)
                    acc[i][j] = fmaf(aa[i], bb[j], acc[i][j]);
        }
        __syncthreads();
    }
    #pragma unroll
    for (int i = 0; i < 4; ++i) {
        int gr = rowBase + ty * 4 + i;
        if (gr >= M) continue;
        #pragma unroll
        for (int j = 0; j < 4; ++j) {
            int gc = tx * 4 + j;
            if (gc < N) C[(size_t)gr * N + gc] = fmaxf(acc[i][j] + bias[gc], 0.f);
        }
    }
}

// ---------------------------------------------------------------------------
// conversions
__global__ __launch_bounds__(256) void cvt_k(const float* __restrict__ in,
                                             ushort* __restrict__ out, long n) {
    long i = ((long)blockIdx.x * 256 + threadIdx.x) * 4;
    if (i >= n) return;
    float4 v = *(const float4*)(in + i);
    ushort4 o;
    o.x = f2bf(v.x); o.y = f2bf(v.y); o.z = f2bf(v.z); o.w = f2bf(v.w);
    *(ushort4*)(out + i) = o;
}

// WencT[c][d] = bf16(W_enc[c/100][d][c%100]), c in [0,512) (pad>=500 -> 0), d in [0,512)
__global__ __launch_bounds__(256) void cvt_wencT_k(const float* __restrict__ W,
                                                   ushort* __restrict__ out) {
    int idx = blockIdx.x * 256 + threadIdx.x;
    int c = idx >> 9, d = idx & 511;
    float v = 0.f;
    if (c < DGCN) {
        int s = c / FSUP, f = c - s * FSUP;
        v = W[((size_t)s * DIN + d) * FSUP + f];
    }
    out[idx] = f2bf(v);
}

// W2aT[j][c] = bf16(W2[c][j]) for c<500, pad c in [500,512) -> 0. j<128.
__global__ __launch_bounds__(256) void cvt_w2aT_k(const float* __restrict__ W2,
                                                  ushort* __restrict__ out) {
    int idx = blockIdx.x * 256 + threadIdx.x;
    int j = idx >> 9, c = idx & 511;
    float v = (c < DGCN) ? W2[(size_t)c * DENC + j] : 0.f;
    out[idx] = f2bf(v);
}

// decWT[b*128+j][k] = bf16(dec_W[b][k][j])
__global__ __launch_bounds__(256) void cvt_decWT_k(const float* __restrict__ W,
                                                   ushort* __restrict__ out) {
    int idx = blockIdx.x * 256 + threadIdx.x;       // 384*128
    int p = idx >> 7, k = idx & 127;
    int b = p >> 7, j = p & 127;
    out[idx] = f2bf(W[((size_t)b * DENC + k) * DENC + j]);
}

// X[n][c] = c<500 ? bf16(relu(hid[c/100][n][c%100])) : 0 ; X [M][512], hid [5][M][100]
__global__ __launch_bounds__(256) void pack_relu_k(const float* __restrict__ hid,
                                                   ushort* __restrict__ X, int M) {
    long idx = (long)blockIdx.x * 256 + threadIdx.x;
    int n = (int)(idx >> 9), c = (int)(idx & 511);
    if (n >= M) return;
    float v = 0.f;
    if (c < DGCN) {
        int s = c / FSUP, f = c - s * FSUP;
        v = hid[((size_t)s * M + n) * FSUP + f];
        v = fmaxf(v, 0.f);
    }
    X[idx] = f2bf(v);
}

// emb[n][j] += sum_h side[n][h] * W2[(500+h)*128 + j]
__global__ __launch_bounds__(256) void accum_side_k(const float* __restrict__ side,
                                                    const float* __restrict__ W2,
                                                    float* __restrict__ emb, int M) {
    __shared__ float Ws[HSIDE][DENC];
    for (int i = threadIdx.x; i < HSIDE * DENC; i += 256)
        Ws[i >> 7][i & 127] = W2[(size_t)(DGCN + (i >> 7)) * DENC + (i & 127)];
    __syncthreads();
    int n = blockIdx.x * 2 + (threadIdx.x >> 7);
    if (n >= M) return;
    int j = threadIdx.x & 127;
    const float* s = side + (size_t)n * HSIDE;
    float a = emb[(size_t)n * DENC + j];
    #pragma unroll 8
    for (int h = 0; h < HSIDE; ++h) a = fmaf(s[h], Ws[h][j], a);
    emb[(size_t)n * DENC + j] = a;
}

// ---------------------------------------------------------------------------
// sparse aggregation (atomics), bf16 tmp [N][512] slice at colOff
__global__ __launch_bounds__(256) void agg_k(
    const int* __restrict__ rows, const int* __restrict__ cols,
    const float* __restrict__ vals,
    const ushort* __restrict__ tmpU, const ushort* __restrict__ tmpV,
    float* __restrict__ hidU, float* __restrict__ hidV, int colOff, int nE)
{
    int e = blockIdx.x * 8 + (threadIdx.x >> 5);
    if (e >= nE) return;
    int lane = threadIdx.x & 31;
    int r = rows[e], c = cols[e];
    float v = vals[e];
    const ushort* tv = tmpV + (size_t)c * 512 + colOff;
    const ushort* tu = tmpU + (size_t)r * 512 + colOff;
    float* hu = hidU + (size_t)r * FSUP;
    float* hv = hidV + (size_t)c * FSUP;
    #pragma unroll
    for (int i = 0; i < 4; ++i) {
        int f = lane + i * 32;
        if (f < FSUP) {
            atomicAdd(&hu[f], v * bf2f(tv[f]));
            atomicAdd(&hv[f], v * bf2f(tu[f]));
        }
    }
}

// ---------------------------------------------------------------------------
// final decoder over edges: basis[b] = dot(Ub[u][b*128..], embV[v]); out = basis@cls
__global__ __launch_bounds__(256) void dec_k(
    const int* __restrict__ ue, const int* __restrict__ ie,
    const float* __restrict__ Ub, const float* __restrict__ embV,
    const float* __restrict__ cls, float* __restrict__ out, int nE)
{
    int e = blockIdx.x * 8 + (threadIdx.x >> 5);
    if (e >= nE) return;
    int lane = threadIdx.x & 31;
    int u = ue[e], v = ie[e];
    const float* pv = embV + (size_t)v * DENC;
    float vb[4];
    #pragma unroll
    for (int i = 0; i < 4; ++i) vb[i] = pv[lane + i * 32];
    float basis[NBAS];
    #pragma unroll
    for (int b = 0; b < NBAS; ++b) {
        const float* pu = Ub + (size_t)u * (NBAS * DENC) + b * DENC;
        float s = 0.f;
        #pragma unroll
        for (int i = 0; i < 4; ++i) s += pu[lane + i * 32] * vb[i];
        #pragma unroll
        for (int off = 16; off; off >>= 1) s += __shfl_xor(s, off, 32);
        basis[b] = s;
    }
    if (lane < NCLS) {
        float o = 0.f;
        #pragma unroll
        for (int b = 0; b < NBAS; ++b) o += basis[b] * cls[b * NCLS + lane];
        out[(size_t)e * NCLS + lane] = o;
    }
}

// ---------------------------------------------------------------------------
extern "C" void kernel_launch(void* const* d_in, const int* in_sizes, int n_in,
                              void* d_out, int out_size, void* d_ws, size_t ws_size,
                              hipStream_t stream) {
    const int*   sup_u  = (const int*)  d_in[0];
    const int*   sup_i  = (const int*)  d_in[1];
    const float* sup_v  = (const float*)d_in[2];
    const float* u_in   = (const float*)d_in[3];
    const float* v_in   = (const float*)d_in[4];
    const float* u_side = (const float*)d_in[5];
    const float* v_side = (const float*)d_in[6];
    const int*   ue     = (const int*)  d_in[7];
    const int*   ie     = (const int*)  d_in[8];
    const float* W_enc  = (const float*)d_in[9];
    const float* Wu1    = (const float*)d_in[10];
    const float* bu1    = (const float*)d_in[11];
    const float* Wi1    = (const float*)d_in[12];
    const float* bi1    = (const float*)d_in[13];
    const float* Wu2    = (const float*)d_in[14];
    const float* Wi2    = (const float*)d_in[15];
    const float* dec_W  = (const float*)d_in[16];
    const float* deccls = (const float*)d_in[17];

    char* ws = (char*)d_ws;
    // hid region @0 (300 MB), overlaid before/after its lifetime:
    float*  hidU   = (float*)(ws);                    // [5][NU][100] f32, ph3-5
    float*  hidV   = (float*)(ws + 200000000LL);      // [5][NV][100]
    ushort* u_bf   = (ushort*)(ws);                   // [NU][512] bf16, ph1-2
    ushort* v_bf   = (ushort*)(ws + 102400000LL);     // [NV][512] bf16
    float*  sideU  = (float*)(ws);                    // [NU][64] f32, ph6+
    float*  sideV  = (float*)(ws + 25600000LL);       // [NV][64]
    float*  embU   = (float*)(ws + 38400000LL);       // [NU][128] f32
    float*  embV   = (float*)(ws + 89600000LL);       // [NV][128] f32
    ushort* embUbf = (ushort*)(ws + 115200000LL);     // [NU][128] bf16
    float*  Ub     = (float*)(ws + 140800000LL);      // [NU][384] f32 (ends 294.4M)
    // tmp/X region @300M (153.6 MB):
    ushort* tmpU   = (ushort*)(ws + 300000000LL);     // [NU][512] bf16 (ph2-3)
    ushort* tmpV   = (ushort*)(ws + 402400000LL);     // [NV][512] bf16
    ushort* Xu     = (ushort*)(ws + 300000000LL);     // [NU][512] bf16 (ph5-6)
    ushort* Xv     = (ushort*)(ws + 402400000LL);     // [NV][512] bf16
    // small weights @453.6M:
    ushort* WencT  = (ushort*)(ws + 453600000LL);     // [512][512]
    ushort* W2uaT  = (ushort*)(ws + 454124288LL);     // [128][512]
    ushort* W2iaT  = (ushort*)(ws + 454255360LL);     // [128][512]
    ushort* decWT  = (ushort*)(ws + 454386432LL);     // [384][128]

    dim3 blk(256);
    const int gu128 = (NU + 127) / 128;   // 782
    const int gv128 = (NV + 127) / 128;   // 391
    const int gu64  = (NU + 63) / 64;     // 1563
    const int gv64  = (NV + 63) / 64;     // 782

    // ---- phase 1: bf16 conversions ----
    cvt_k<<<dim3((NU * 512 / 4 + 255) / 256), blk, 0, stream>>>(u_in, u_bf, (long)NU * 512);
    cvt_k<<<dim3((NV * 512 / 4 + 255) / 256), blk, 0, stream>>>(v_in, v_bf, (long)NV * 512);
    cvt_wencT_k<<<dim3(512 * 512 / 256), blk, 0, stream>>>(W_enc, WencT);
    cvt_w2aT_k<<<dim3(128 * 512 / 256), blk, 0, stream>>>(Wu2, W2uaT);
    cvt_w2aT_k<<<dim3(128 * 512 / 256), blk, 0, stream>>>(Wi2, W2iaT);
    cvt_decWT_k<<<dim3(384 * 128 / 256), blk, 0, stream>>>(dec_W, decWT);

    // ---- phase 2: fused encoder GEMMs (bf16 out) ----
    gemm_bf16_k<1><<<dim3(gu128, 4), blk, 0, stream>>>(u_bf, WencT, tmpU, NU, 512, 512, 512);
    gemm_bf16_k<1><<<dim3(gv128, 4), blk, 0, stream>>>(v_bf, WencT, tmpV, NV, 512, 512, 512);

    // ---- phase 3: zero hid, aggregate per support ----
    hipMemsetAsync(ws, 0, 300000000LL, stream);
    for (int k = 0; k < KSUP; ++k) {
        agg_k<<<dim3(ESUP / 8), blk, 0, stream>>>(
            sup_u + (size_t)k * ESUP, sup_i + (size_t)k * ESUP, sup_v + (size_t)k * ESUP,
            tmpU, tmpV,
            hidU + (size_t)k * NU * FSUP, hidV + (size_t)k * NV * FSUP,
            k * FSUP, ESUP);
    }

    // ---- phase 5: pack relu(hid) -> X bf16 (frees hid region afterwards) ----
    pack_relu_k<<<dim3(NU * 2), blk, 0, stream>>>(hidU, Xu, NU);
    pack_relu_k<<<dim3(NV * 2), blk, 0, stream>>>(hidV, Xv, NV);

    // ---- phase 6: side dense (fp32) into freed hid region ----
    gemm_side_k<<<dim3(gu64), blk, 0, stream>>>(u_side, Wu1, bu1, sideU, NU, HSIDE, DSIDE);
    gemm_side_k<<<dim3(gv64), blk, 0, stream>>>(v_side, Wi1, bi1, sideV, NV, HSIDE, DSIDE);

    // ---- dense2: emb = X @ W2aT (MFMA), then += side part ----
    gemm_bf16_k<0><<<dim3(gu128, 1), blk, 0, stream>>>(Xu, W2uaT, embU, NU, 128, 512, 128);
    gemm_bf16_k<0><<<dim3(gv128, 1), blk, 0, stream>>>(Xv, W2iaT, embV, NV, 128, 512, 128);
    accum_side_k<<<dim3((NU + 1) / 2), blk, 0, stream>>>(sideU, Wu2, embU, NU);
    accum_side_k<<<dim3((NV + 1) / 2), blk, 0, stream>>>(sideV, Wi2, embV, NV);

    // ---- decoder precompute: Ub = embU_bf @ decWT (N=384) ----
    cvt_k<<<dim3((NU * 128 / 4 + 255) / 256), blk, 0, stream>>>(embU, embUbf, (long)NU * 128);
    gemm_bf16_k<0><<<dim3(gu128, 3), blk, 0, stream>>>(embUbf, decWT, Ub, NU, 384, 128, 384);

    // ---- final decoder over edges ----
    dec_k<<<dim3(NE / 8), blk, 0, stream>>>(ue, ie, Ub, embV, deccls, (float*)d_out, NE);
}

// Round 3
// 2269.615 us; speedup vs baseline: 2.0787x; 1.3075x over previous
//
#include <hip/hip_runtime.h>

// Problem constants (fixed by the reference)
#define NU 100000
#define NV 50000
#define KSUP 5
#define ESUP 400000
#define NEDGE (KSUP * ESUP)   // 2,000,000
#define NE 500000
#define DIN 512
#define DGCN 500
#define FSUP 100     // DGCN / KSUP
#define DSIDE 128
#define HSIDE 64
#define DENC 128
#define NBAS 3
#define NCLS 5

__device__ __forceinline__ ushort f2bf(float x) {
    union { float f; unsigned u; } c; c.f = x;
    unsigned r = (c.u + 0x7FFFu + ((c.u >> 16) & 1u)) >> 16;   // RNE
    return (ushort)r;
}
__device__ __forceinline__ float bf2f(ushort h) {
    union { unsigned u; float f; } c; c.u = ((unsigned)h) << 16;
    return c.f;
}

typedef __attribute__((ext_vector_type(4))) float f32x4;
typedef __attribute__((ext_vector_type(8))) short bf16x8;
typedef __attribute__((address_space(3))) void lds_void;
typedef const __attribute__((address_space(1))) void glob_void;

// ---------------------------------------------------------------------------
// bf16 MFMA GEMM: C[M,N] = A[M,K](bf16,K-major) @ BT[N,K](bf16,K-major)^T
// 128x128 tile, BK=64, 4 waves (2x2). LDS XOR-swizzled via pre-swizzled
// global source (rule #21). STORE_BF16: 1 -> C ushort, 0 -> C float.
template<int STORE_BF16>
__global__ __launch_bounds__(256) void gemm_bf16_k(
    const ushort* __restrict__ A, const ushort* __restrict__ BT,
    void* __restrict__ Cout, int M, int N, int K, int ldc)
{
    __shared__ ushort As[128 * 64];
    __shared__ ushort Bs[128 * 64];
    const int t = threadIdx.x;
    const int lane = t & 63;
    const int w = t >> 6;
    const int wr = w >> 1, wc = w & 1;
    const int rowBase = blockIdx.x * 128;
    const int colBase = blockIdx.y * 128;

    f32x4 acc[4][4] = {};

    for (int k0 = 0; k0 < K; k0 += 64) {
        #pragma unroll
        for (int i = 0; i < 4; ++i) {
            int chi = i * 256 + t;
            int r = chi >> 3;
            int c = (((chi >> 3) & 7) ^ (chi & 7)) * 8;
            int ga = rowBase + r; if (ga > M - 1) ga = M - 1;
            __builtin_amdgcn_global_load_lds(
                (glob_void*)(A + (size_t)ga * K + k0 + c),
                (lds_void*)(As + (size_t)chi * 8), 16, 0, 0);
            int gb = colBase + r; if (gb > N - 1) gb = N - 1;
            __builtin_amdgcn_global_load_lds(
                (glob_void*)(BT + (size_t)gb * K + k0 + c),
                (lds_void*)(Bs + (size_t)chi * 8), 16, 0, 0);
        }
        __syncthreads();

        #pragma unroll
        for (int kk = 0; kk < 2; ++kk) {
            bf16x8 af[4], bfr[4];
            const int cb2 = (kk * 32 + (lane >> 4) * 8) * 2;
            #pragma unroll
            for (int mi = 0; mi < 4; ++mi) {
                int r = wr * 64 + mi * 16 + (lane & 15);
                int off = (r * 128 + cb2) ^ ((r & 7) << 4);
                af[mi] = *(const bf16x8*)((const char*)As + off);
            }
            #pragma unroll
            for (int nj = 0; nj < 4; ++nj) {
                int r = wc * 64 + nj * 16 + (lane & 15);
                int off = (r * 128 + cb2) ^ ((r & 7) << 4);
                bfr[nj] = *(const bf16x8*)((const char*)Bs + off);
            }
            #pragma unroll
            for (int mi = 0; mi < 4; ++mi)
                #pragma unroll
                for (int nj = 0; nj < 4; ++nj)
                    acc[mi][nj] = __builtin_amdgcn_mfma_f32_16x16x32_bf16(
                        af[mi], bfr[nj], acc[mi][nj], 0, 0, 0);
        }
        __syncthreads();
    }

    #pragma unroll
    for (int mi = 0; mi < 4; ++mi) {
        #pragma unroll
        for (int q = 0; q < 4; ++q) {
            int gr = rowBase + wr * 64 + mi * 16 + (lane >> 4) * 4 + q;
            if (gr >= M) continue;
            #pragma unroll
            for (int nj = 0; nj < 4; ++nj) {
                int gc = colBase + wc * 64 + nj * 16 + (lane & 15);
                float v = acc[mi][nj][q];
                if (STORE_BF16)
                    ((ushort*)Cout)[(size_t)gr * ldc + gc] = f2bf(v);
                else
                    ((float*)Cout)[(size_t)gr * ldc + gc] = v;
            }
        }
    }
}

// ---------------------------------------------------------------------------
// fp32 tiled GEMM (side dense only): C = relu(A@B + bias)
#define BM 64
#define BN 64
#define BK 16
__global__ __launch_bounds__(256) void gemm_side_k(
    const float* __restrict__ A, const float* __restrict__ B,
    const float* __restrict__ bias, float* __restrict__ C,
    int M, int N, int K)
{
    __shared__ float As[BK][BM + 4];
    __shared__ float Bs[BK][BN + 4];
    const int t = threadIdx.x;
    const int rowBase = blockIdx.x * BM;
    const int ty = t >> 4, tx = t & 15;
    float acc[4][4] = {};

    for (int k0 = 0; k0 < K; k0 += BK) {
        #pragma unroll
        for (int p = 0; p < 4; ++p) {
            int r = p * 16 + (t >> 4), kk = t & 15;
            int gr = rowBase + r, gk = k0 + kk;
            As[kk][r] = (gr < M && gk < K) ? A[(size_t)gr * K + gk] : 0.f;
        }
        #pragma unroll
        for (int p = 0; p < 4; ++p) {
            int kk = p * 4 + (t >> 6), j = t & 63;
            int gk = k0 + kk;
            Bs[kk][j] = (j < N && gk < K) ? B[(size_t)gk * N + j] : 0.f;
        }
        __syncthreads();
        #pragma unroll
        for (int kk = 0; kk < BK; ++kk) {
            float4 a4 = *reinterpret_cast<const float4*>(&As[kk][ty * 4]);
            float4 b4 = *reinterpret_cast<const float4*>(&Bs[kk][tx * 4]);
            float aa[4] = {a4.x, a4.y, a4.z, a4.w};
            float bb[4] = {b4.x, b4.y, b4.z, b4.w};
            #pragma unroll
            for (int i = 0; i < 4; ++i)
                #pragma unroll
                for (int j = 0; j < 4; ++j)
                    acc[i][j] = fmaf(aa[i], bb[j], acc[i][j]);
        }
        __syncthreads();
    }
    #pragma unroll
    for (int i = 0; i < 4; ++i) {
        int gr = rowBase + ty * 4 + i;
        if (gr >= M) continue;
        #pragma unroll
        for (int j = 0; j < 4; ++j) {
            int gc = tx * 4 + j;
            if (gc < N) C[(size_t)gr * N + gc] = fmaxf(acc[i][j] + bias[gc], 0.f);
        }
    }
}

// ---------------------------------------------------------------------------
// conversions
__global__ __launch_bounds__(256) void cvt_k(const float* __restrict__ in,
                                             ushort* __restrict__ out, long n) {
    long i = ((long)blockIdx.x * 256 + threadIdx.x) * 4;
    if (i >= n) return;
    float4 v = *(const float4*)(in + i);
    ushort4 o;
    o.x = f2bf(v.x); o.y = f2bf(v.y); o.z = f2bf(v.z); o.w = f2bf(v.w);
    *(ushort4*)(out + i) = o;
}

__global__ __launch_bounds__(256) void cvt_wencT_k(const float* __restrict__ W,
                                                   ushort* __restrict__ out) {
    int idx = blockIdx.x * 256 + threadIdx.x;
    int c = idx >> 9, d = idx & 511;
    float v = 0.f;
    if (c < DGCN) {
        int s = c / FSUP, f = c - s * FSUP;
        v = W[((size_t)s * DIN + d) * FSUP + f];
    }
    out[idx] = f2bf(v);
}

__global__ __launch_bounds__(256) void cvt_w2aT_k(const float* __restrict__ W2,
                                                  ushort* __restrict__ out) {
    int idx = blockIdx.x * 256 + threadIdx.x;
    int j = idx >> 9, c = idx & 511;
    float v = (c < DGCN) ? W2[(size_t)c * DENC + j] : 0.f;
    out[idx] = f2bf(v);
}

__global__ __launch_bounds__(256) void cvt_decWT_k(const float* __restrict__ W,
                                                   ushort* __restrict__ out) {
    int idx = blockIdx.x * 256 + threadIdx.x;       // 384*128
    int p = idx >> 7, k = idx & 127;
    int b = p >> 7, j = p & 127;
    out[idx] = f2bf(W[((size_t)b * DENC + k) * DENC + j]);
}

// emb[n][j] += sum_h side[n][h] * W2[(500+h)*128 + j]
__global__ __launch_bounds__(256) void accum_side_k(const float* __restrict__ side,
                                                    const float* __restrict__ W2,
                                                    float* __restrict__ emb, int M) {
    __shared__ float Ws[HSIDE][DENC];
    for (int i = threadIdx.x; i < HSIDE * DENC; i += 256)
        Ws[i >> 7][i & 127] = W2[(size_t)(DGCN + (i >> 7)) * DENC + (i & 127)];
    __syncthreads();
    int n = blockIdx.x * 2 + (threadIdx.x >> 7);
    if (n >= M) return;
    int j = threadIdx.x & 127;
    const float* s = side + (size_t)n * HSIDE;
    float a = emb[(size_t)n * DENC + j];
    #pragma unroll 8
    for (int h = 0; h < HSIDE; ++h) a = fmaf(s[h], Ws[h][j], a);
    emb[(size_t)n * DENC + j] = a;
}

// ---------------------------------------------------------------------------
// CSR build: histogram, 3-kernel exclusive scan, scatter
__global__ __launch_bounds__(256) void hist_k(
    const int* __restrict__ su, const int* __restrict__ si,
    int* __restrict__ histU, int* __restrict__ histV)
{
    int e = blockIdx.x * 256 + threadIdx.x;
    if (e >= NEDGE) return;
    int k = e / ESUP;
    atomicAdd(&histU[k * NU + su[e]], 1);
    atomicAdd(&histV[k * NV + si[e]], 1);
}

__global__ __launch_bounds__(256) void scan_reduce_k(const int* __restrict__ in,
                                                     int* __restrict__ bs, int n) {
    __shared__ int sm[256];
    int base = blockIdx.x * 2048 + threadIdx.x * 8;
    int s = 0;
    #pragma unroll
    for (int i = 0; i < 8; ++i) { int idx = base + i; if (idx < n) s += in[idx]; }
    sm[threadIdx.x] = s; __syncthreads();
    for (int off = 128; off; off >>= 1) {
        if (threadIdx.x < off) sm[threadIdx.x] += sm[threadIdx.x + off];
        __syncthreads();
    }
    if (threadIdx.x == 0) bs[blockIdx.x] = sm[0];
}

// single block: exclusive scan of bs[0..nb), nb <= 256
__global__ __launch_bounds__(256) void scan_bs_k(int* __restrict__ bs, int nb) {
    __shared__ int sm[256];
    int t = threadIdx.x;
    int v = (t < nb) ? bs[t] : 0;
    sm[t] = v; __syncthreads();
    for (int off = 1; off < 256; off <<= 1) {
        int add = (t >= off) ? sm[t - off] : 0;
        __syncthreads();
        sm[t] += add;
        __syncthreads();
    }
    if (t < nb) bs[t] = sm[t] - v;   // exclusive
}

__global__ __launch_bounds__(256) void scan_write_k(const int* __restrict__ in,
                                                    const int* __restrict__ bs,
                                                    int* __restrict__ out, int n) {
    __shared__ int sm[256];
    int t = threadIdx.x;
    int base = blockIdx.x * 2048 + t * 8;
    int loc[8]; int s = 0;
    #pragma unroll
    for (int i = 0; i < 8; ++i) {
        int idx = base + i;
        loc[i] = (idx < n) ? in[idx] : 0;
        s += loc[i];
    }
    sm[t] = s; __syncthreads();
    int sv = s;
    for (int off = 1; off < 256; off <<= 1) {
        int add = (t >= off) ? sm[t - off] : 0;
        __syncthreads();
        sm[t] += add;
        __syncthreads();
    }
    int thOff = bs[blockIdx.x] + sm[t] - sv;
    int run = 0;
    #pragma unroll
    for (int i = 0; i < 8; ++i) {
        int idx = base + i;
        if (idx < n) out[idx] = thOff + run;
        run += loc[i];
    }
}

__global__ __launch_bounds__(256) void scatter_k(
    const int* __restrict__ su, const int* __restrict__ si,
    const float* __restrict__ sv,
    int* __restrict__ posU, int* __restrict__ posV,
    int* __restrict__ eColU, float* __restrict__ eValU,
    int* __restrict__ eRowV, float* __restrict__ eValV)
{
    int e = blockIdx.x * 256 + threadIdx.x;
    if (e >= NEDGE) return;
    int k = e / ESUP;
    int r = su[e], c = si[e];
    float v = sv[e];
    int pu = atomicAdd(&posU[k * NU + r], 1);
    eColU[pu] = c; eValU[pu] = v;
    int pv = atomicAdd(&posV[k * NV + c], 1);
    eRowV[pv] = r; eValV[pv] = v;
}

// ---------------------------------------------------------------------------
// CSR aggregation for support k, both directions. 128 threads per node,
// register accumulation, single coalesced write of bf16(relu(acc)) directly
// into the packed X[n][512] layout (col slice [k*100,(k+1)*100)).
// k==4 additionally zeroes pad cols [500,512).
__global__ __launch_bounds__(256) void agg_csr_k(
    const int* __restrict__ rowPtrU, const int* __restrict__ eColU,
    const float* __restrict__ eValU,
    const int* __restrict__ rowPtrV, const int* __restrict__ eRowV,
    const float* __restrict__ eValV,
    const ushort* __restrict__ tmpU, const ushort* __restrict__ tmpV,
    ushort* __restrict__ Xu, ushort* __restrict__ Xv, int k)
{
    int half = blockIdx.x;
    int j = threadIdx.x & 127;
    int sub = threadIdx.x >> 7;
    if (half < NU / 2) {
        int n = half * 2 + sub;
        int g = k * NU + n;
        int s = rowPtrU[g];
        int e = (g == KSUP * NU - 1) ? NEDGE : rowPtrU[g + 1];
        float acc = 0.f;
        for (int p = s; p < e; ++p) {
            int c = eColU[p]; float v = eValU[p];
            if (j < FSUP) acc += v * bf2f(tmpV[(size_t)c * 512 + k * FSUP + j]);
        }
        if (j < FSUP) Xu[(size_t)n * 512 + k * FSUP + j] = f2bf(fmaxf(acc, 0.f));
        else if (k == 4 && j < 112) Xu[(size_t)n * 512 + 400 + j] = 0;
    } else {
        int n = (half - NU / 2) * 2 + sub;
        int g = k * NV + n;
        int s = rowPtrV[g];
        int e = (g == KSUP * NV - 1) ? NEDGE : rowPtrV[g + 1];
        float acc = 0.f;
        for (int p = s; p < e; ++p) {
            int r = eRowV[p]; float v = eValV[p];
            if (j < FSUP) acc += v * bf2f(tmpU[(size_t)r * 512 + k * FSUP + j]);
        }
        if (j < FSUP) Xv[(size_t)n * 512 + k * FSUP + j] = f2bf(fmaxf(acc, 0.f));
        else if (k == 4 && j < 112) Xv[(size_t)n * 512 + 400 + j] = 0;
    }
}

// ---------------------------------------------------------------------------
// final decoder: basis[b] = dot(bf16 Ub[u][b*128..], embV[v]); out = basis@cls
__global__ __launch_bounds__(256) void dec_k(
    const int* __restrict__ ue, const int* __restrict__ ie,
    const ushort* __restrict__ Ub, const float* __restrict__ embV,
    const float* __restrict__ cls, float* __restrict__ out, int nE)
{
    int e = blockIdx.x * 8 + (threadIdx.x >> 5);
    if (e >= nE) return;
    int lane = threadIdx.x & 31;
    int u = ue[e], v = ie[e];
    const float* pv = embV + (size_t)v * DENC;
    float vb[4];
    #pragma unroll
    for (int i = 0; i < 4; ++i) vb[i] = pv[lane + i * 32];
    float basis[NBAS];
    #pragma unroll
    for (int b = 0; b < NBAS; ++b) {
        const ushort* pu = Ub + (size_t)u * (NBAS * DENC) + b * DENC;
        float s = 0.f;
        #pragma unroll
        for (int i = 0; i < 4; ++i) s += bf2f(pu[lane + i * 32]) * vb[i];
        #pragma unroll
        for (int off = 16; off; off >>= 1) s += __shfl_xor(s, off, 32);
        basis[b] = s;
    }
    if (lane < NCLS) {
        float o = 0.f;
        #pragma unroll
        for (int b = 0; b < NBAS; ++b) o += basis[b] * cls[b * NCLS + lane];
        out[(size_t)e * NCLS + lane] = o;
    }
}

// ---------------------------------------------------------------------------
extern "C" void kernel_launch(void* const* d_in, const int* in_sizes, int n_in,
                              void* d_out, int out_size, void* d_ws, size_t ws_size,
                              hipStream_t stream) {
    const int*   sup_u  = (const int*)  d_in[0];
    const int*   sup_i  = (const int*)  d_in[1];
    const float* sup_v  = (const float*)d_in[2];
    const float* u_in   = (const float*)d_in[3];
    const float* v_in   = (const float*)d_in[4];
    const float* u_side = (const float*)d_in[5];
    const float* v_side = (const float*)d_in[6];
    const int*   ue     = (const int*)  d_in[7];
    const int*   ie     = (const int*)  d_in[8];
    const float* W_enc  = (const float*)d_in[9];
    const float* Wu1    = (const float*)d_in[10];
    const float* bu1    = (const float*)d_in[11];
    const float* Wi1    = (const float*)d_in[12];
    const float* bi1    = (const float*)d_in[13];
    const float* Wu2    = (const float*)d_in[14];
    const float* Wi2    = (const float*)d_in[15];
    const float* dec_W  = (const float*)d_in[16];
    const float* deccls = (const float*)d_in[17];

    char* ws = (char*)d_ws;
    // Region @0 (timeline-overlaid):
    //   ph1-2: u_bf [NU][512] bf16 @0 (102.4M), v_bf [NV][512] @102.4M (51.2M)
    //   ph3+ : Xu @0, Xv @102.4M (same sizes; written by agg after u_bf dead)
    //   ph7  : embUbf @0 (25.6M), Ub bf16 [NU][384] @26M (76.8M)  (X dead)
    ushort* u_bf   = (ushort*)(ws);
    ushort* v_bf   = (ushort*)(ws + 102400000LL);
    ushort* Xu     = (ushort*)(ws);
    ushort* Xv     = (ushort*)(ws + 102400000LL);
    ushort* embUbf = (ushort*)(ws);
    ushort* Ub     = (ushort*)(ws + 26000000LL);
    // CSR region @156M (dead after agg):
    int*    histU  = (int*)(ws + 156000000LL);          // [5][NU]
    int*    histV  = (int*)(ws + 158000000LL);          // [5][NV]
    int*    rowPtrU= (int*)(ws + 159000000LL);          // [5][NU]
    int*    rowPtrV= (int*)(ws + 161000000LL);          // [5][NV]
    int*    posU   = (int*)(ws + 162000000LL);          // [5][NU]
    int*    posV   = (int*)(ws + 164000000LL);          // [5][NV]
    int*    bsums  = (int*)(ws + 165000000LL);          // 1024
    int*    eColU  = (int*)(ws + 165010000LL);          // [2M]
    float*  eValU  = (float*)(ws + 173010000LL);        // [2M]
    int*    eRowV  = (int*)(ws + 181010000LL);          // [2M]
    float*  eValV  = (float*)(ws + 189010000LL);        // [2M] ends 197.01M
    // Post-agg region (over dead CSR):
    float*  sideU  = (float*)(ws + 200000000LL);        // [NU][64] (25.6M)
    float*  sideV  = (float*)(ws + 226000000LL);        // [NV][64] (12.8M)
    float*  embU   = (float*)(ws + 240000000LL);        // [NU][128] (51.2M)
    float*  embV   = (float*)(ws + 300000000LL);        // [NV][128] (25.6M, over dead tmpU)
    // tmp region @300M (live ph2..agg only; embV overlays after)
    ushort* tmpU   = (ushort*)(ws + 300000000LL);       // [NU][512] bf16
    ushort* tmpV   = (ushort*)(ws + 402400000LL);       // [NV][512] bf16
    // weights @453.6M:
    ushort* WencT  = (ushort*)(ws + 453600000LL);       // [512][512]
    ushort* W2uaT  = (ushort*)(ws + 454124288LL);       // [128][512]
    ushort* W2iaT  = (ushort*)(ws + 454255360LL);       // [128][512]
    ushort* decWT  = (ushort*)(ws + 454386432LL);       // [384][128]

    dim3 blk(256);
    const int gu128 = (NU + 127) / 128;   // 782
    const int gv128 = (NV + 127) / 128;   // 391
    const int gu64  = (NU + 63) / 64;     // 1563
    const int gv64  = (NV + 63) / 64;     // 782
    const int gE    = (NEDGE + 255) / 256;

    // ---- phase 1: bf16 conversions + CSR build ----
    cvt_k<<<dim3((NU * 512 / 4 + 255) / 256), blk, 0, stream>>>(u_in, u_bf, (long)NU * 512);
    cvt_k<<<dim3((NV * 512 / 4 + 255) / 256), blk, 0, stream>>>(v_in, v_bf, (long)NV * 512);
    cvt_wencT_k<<<dim3(512 * 512 / 256), blk, 0, stream>>>(W_enc, WencT);
    cvt_w2aT_k<<<dim3(128 * 512 / 256), blk, 0, stream>>>(Wu2, W2uaT);
    cvt_w2aT_k<<<dim3(128 * 512 / 256), blk, 0, stream>>>(Wi2, W2iaT);
    cvt_decWT_k<<<dim3(384 * 128 / 256), blk, 0, stream>>>(dec_W, decWT);

    hipMemsetAsync(histU, 0, 3000000LL, stream);   // histU + histV contiguous
    hist_k<<<dim3(gE), blk, 0, stream>>>(sup_u, sup_i, histU, histV);
    // scan U (n = 500000, nb = 245)
    scan_reduce_k<<<dim3(245), blk, 0, stream>>>(histU, bsums, KSUP * NU);
    scan_bs_k<<<dim3(1), blk, 0, stream>>>(bsums, 245);
    scan_write_k<<<dim3(245), blk, 0, stream>>>(histU, bsums, rowPtrU, KSUP * NU);
    // scan V (n = 250000, nb = 123)
    scan_reduce_k<<<dim3(123), blk, 0, stream>>>(histV, bsums, KSUP * NV);
    scan_bs_k<<<dim3(1), blk, 0, stream>>>(bsums, 123);
    scan_write_k<<<dim3(123), blk, 0, stream>>>(histV, bsums, rowPtrV, KSUP * NV);
    hipMemcpyAsync(posU, rowPtrU, (size_t)KSUP * NU * 4, hipMemcpyDeviceToDevice, stream);
    hipMemcpyAsync(posV, rowPtrV, (size_t)KSUP * NV * 4, hipMemcpyDeviceToDevice, stream);
    scatter_k<<<dim3(gE), blk, 0, stream>>>(sup_u, sup_i, sup_v,
                                            posU, posV, eColU, eValU, eRowV, eValV);

    // ---- phase 2: fused encoder GEMMs (bf16 out) ----
    gemm_bf16_k<1><<<dim3(gu128, 4), blk, 0, stream>>>(u_bf, WencT, tmpU, NU, 512, 512, 512);
    gemm_bf16_k<1><<<dim3(gv128, 4), blk, 0, stream>>>(v_bf, WencT, tmpV, NV, 512, 512, 512);

    // ---- phase 3: CSR aggregation, writes packed relu'd X directly ----
    for (int k = 0; k < KSUP; ++k) {
        agg_csr_k<<<dim3(NU / 2 + NV / 2), blk, 0, stream>>>(
            rowPtrU, eColU, eValU, rowPtrV, eRowV, eValV,
            tmpU, tmpV, Xu, Xv, k);
    }

    // ---- phase 4: side dense (fp32) ----
    gemm_side_k<<<dim3(gu64), blk, 0, stream>>>(u_side, Wu1, bu1, sideU, NU, HSIDE, DSIDE);
    gemm_side_k<<<dim3(gv64), blk, 0, stream>>>(v_side, Wi1, bi1, sideV, NV, HSIDE, DSIDE);

    // ---- phase 5: dense2 = X @ W2aT (MFMA) + side part ----
    gemm_bf16_k<0><<<dim3(gu128, 1), blk, 0, stream>>>(Xu, W2uaT, embU, NU, 128, 512, 128);
    gemm_bf16_k<0><<<dim3(gv128, 1), blk, 0, stream>>>(Xv, W2iaT, embV, NV, 128, 512, 128);
    accum_side_k<<<dim3((NU + 1) / 2), blk, 0, stream>>>(sideU, Wu2, embU, NU);
    accum_side_k<<<dim3((NV + 1) / 2), blk, 0, stream>>>(sideV, Wi2, embV, NV);

    // ---- phase 6: decoder precompute Ub (bf16 out) ----
    cvt_k<<<dim3((NU * 128 / 4 + 255) / 256), blk, 0, stream>>>(embU, embUbf, (long)NU * 128);
    gemm_bf16_k<1><<<dim3(gu128, 3), blk, 0, stream>>>(embUbf, decWT, Ub, NU, 384, 128, 384);

    // ---- phase 7: final decoder over edges ----
    dec_k<<<dim3(NE / 8), blk, 0, stream>>>(ue, ie, Ub, embV, deccls, (float*)d_out, NE);
}